// Round 1
// baseline (1723.168 us; speedup 1.0000x reference)
//
#include <hip/hip_runtime.h>
#include <math.h>

#define NQ 6
#define BATCH 256
#define SEQ 512
#define SD_STRIDE 56   // floats per (b,t) record: dt[6] cosh[6] sinh[6] Cc[18] term[18] pad[2]

__device__ __forceinline__ float shx(float v, int m) { return __shfl_xor(v, m, 64); }

// ---------------------------------------------------------------------------
// Prep kernel: per (b,t) compute dt_angles, half-angle sin/cos for final RY
// layer, C @ Wc.T coefficients, and D*tile(angles,3) term. 54 floats packed.
// ---------------------------------------------------------------------------
__global__ __launch_bounds__(256) void prep_kernel(
    const float* __restrict__ angles, const float* __restrict__ Wx,
    const float* __restrict__ Wdt, const float* __restrict__ bdt,
    const float* __restrict__ D, const float* __restrict__ Wc,
    float* __restrict__ sd)
{
    int gid = blockIdx.x * blockDim.x + threadIdx.x;  // b*SEQ + t
    if (gid >= BATCH * SEQ) return;
    const float* a = angles + (size_t)gid * 6;
    float ang[6];
#pragma unroll
    for (int i = 0; i < 6; i++) ang[i] = a[i];

    // dt_raw = angles @ Wx.T rows 0..2  (DT_RANK = 3)
    float dtr[3];
#pragma unroll
    for (int r = 0; r < 3; r++) {
        float s = 0.f;
#pragma unroll
        for (int k = 0; k < 6; k++) s += ang[k] * Wx[r * 6 + k];
        dtr[r] = s;
    }
    float* rec = sd + (size_t)gid * SD_STRIDE;

    // dt = tanh(softplus(dt_raw @ Wdt.T + bdt)) * pi
    float dtv[6];
#pragma unroll
    for (int i = 0; i < 6; i++) {
        float x = bdt[i];
#pragma unroll
        for (int r = 0; r < 3; r++) x += dtr[r] * Wdt[i * 3 + r];
        float sp = (x > 15.f) ? x : log1pf(expf(x));
        dtv[i] = tanhf(sp) * 3.14159265358979323846f;
        rec[i] = dtv[i];
        // final RY layer angle theta = angles_i * dt_i ; store half-angle sincos
        float th = 0.5f * ang[i] * dtv[i];
        rec[6 + i]  = cosf(th);
        rec[12 + i] = sinf(th);
    }
    // C = x_dbc[..., 9:15] -> rows 9..14 of Wx ; Cc = C @ Wc.T
    float C[6];
#pragma unroll
    for (int i = 0; i < 6; i++) {
        float s = 0.f;
#pragma unroll
        for (int k = 0; k < 6; k++) s += ang[k] * Wx[(9 + i) * 6 + k];
        C[i] = s;
    }
#pragma unroll
    for (int j = 0; j < 18; j++) {
        float s = 0.f;
#pragma unroll
        for (int i = 0; i < 6; i++) s += C[i] * Wc[j * 6 + i];
        rec[18 + j] = s;
        rec[36 + j] = D[j] * ang[j % 6];   // D * concat([angles]*3)
    }
}

// ---------------------------------------------------------------------------
// Step kernel: one block (1 wave, 64 lanes) per batch element; lane = amplitude.
// Qubit i <-> bit (5-i) of the amplitude/lane index (reference axis order).
// Sequential scan over SEQ steps with h-feedback.
// ---------------------------------------------------------------------------
__global__ __launch_bounds__(64, 1) void step_kernel(
    const float* __restrict__ sd, const float* __restrict__ pc,
    const float* __restrict__ qp, const float* __restrict__ cp,
    float* __restrict__ out)
{
    const int lane = threadIdx.x;
    const int b = blockIdx.x;

    // per-lane bit constants
    int bitv[6];
    float sgn[6];
#pragma unroll
    for (int i = 0; i < 6; i++) {
        int bit = (lane >> (5 - i)) & 1;
        bitv[i] = bit;
        sgn[i] = bit ? 0.5f : -0.5f;   // RZ diag phase: theta*(bit - 1/2)
    }

    // inverse permutation of the per-degree CNOT block.
    // Gate list L (applied first->last): (0,1)(1,2)(2,3)(3,4)(4,5) (5,0) (5,4)(4,3)(3,2)(2,1)(1,0)
    // new_state(l) = old_state(pi^{-1}(l)); pi^{-1}(x) applies L reversed to index x.
    int src;
    {
        const int cs[11] = {0,1,2,3,4, 5, 5,4,3,2,1};
        const int ts[11] = {1,2,3,4,5, 0, 4,3,2,1,0};
        int x = lane;
#pragma unroll
        for (int k = 10; k >= 0; k--) {
            int cb = (x >> (5 - cs[k])) & 1;
            x ^= cb << (5 - ts[k]);
        }
        src = x;
    }

    // QSVT angle coefficients u[d][i] = pc[d]*pi*(qp[6d+i] or 1 for d==3)
    float u[4][6];
#pragma unroll
    for (int d = 0; d < 4; d++) {
        float pcv = pc[d] * 3.14159265358979323846f;
#pragma unroll
        for (int i = 0; i < 6; i++) u[d][i] = pcv * (d < 3 ? qp[d * 6 + i] : 1.0f);
    }

    // Fused ansatz single-qubit gates G = RZ*RY*RX (uniform, once per block)
    float G00r[2][6], G00i[2][6], G01r[2][6], G01i[2][6];
    float G10r[2][6], G10i[2][6], G11r[2][6], G11i[2][6];
    float CR1c[2][6], CR1s[2][6], CR2c[2][6], CR2s[2][6];
#pragma unroll
    for (int l = 0; l < 2; l++) {
#pragma unroll
        for (int i = 0; i < 6; i++) {
            float ax = cp[l * 30 + i * 3 + 0];
            float ay = cp[l * 30 + i * 3 + 1];
            float az = cp[l * 30 + i * 3 + 2];
            float ca = cosf(0.5f * ax), sa = sinf(0.5f * ax);
            float cb = cosf(0.5f * ay), sb = sinf(0.5f * ay);
            float cg = cosf(0.5f * az), sg = sinf(0.5f * az);
            // M1 = RY*RX
            float m00r = cb * ca, m00i =  sb * sa;
            float m01r = -sb * ca, m01i = -cb * sa;
            float m10r =  sb * ca, m10i = -cb * sa;
            float m11r =  cb * ca, m11i = -sb * sa;
            // G row0 = (cg - i sg)*M1row0 ; row1 = (cg + i sg)*M1row1
            G00r[l][i] = cg * m00r + sg * m00i; G00i[l][i] = cg * m00i - sg * m00r;
            G01r[l][i] = cg * m01r + sg * m01i; G01i[l][i] = cg * m01i - sg * m01r;
            G10r[l][i] = cg * m10r - sg * m10i; G10i[l][i] = cg * m10i + sg * m10r;
            G11r[l][i] = cg * m11r - sg * m11i; G11i[l][i] = cg * m11i + sg * m11r;
            float t1 = cp[l * 30 + 18 + i];        // ring1: ctrl i, tgt (i+1)%6
            CR1c[l][i] = cosf(0.5f * t1); CR1s[l][i] = sinf(0.5f * t1);
            float t2 = cp[l * 30 + 24 + (5 - i)];  // ring2: ctrl i, tgt (i-1)%6, applied i=5..0
            CR2c[l][i] = cosf(0.5f * t2); CR2s[l][i] = sinf(0.5f * t2);
        }
    }

    float h[6];
#pragma unroll
    for (int i = 0; i < 6; i++) h[i] = 0.f;

    const float* sdb = sd + (size_t)b * SEQ * SD_STRIDE;
    float* outb = out + (size_t)b * SEQ * 18;

    for (int t = 0; t < SEQ; t++) {
        const float* r = sdb + t * SD_STRIDE;
        float dtv[6], chh[6], shh[6];
#pragma unroll
        for (int i = 0; i < 6; i++) { dtv[i] = r[i]; chh[i] = r[6 + i]; shh[i] = r[12 + i]; }

        // ---- initial product state: RY(h_i) layer applied to |0..0> ----
        float re, im = 0.f;
        {
            float prod = 1.f;
#pragma unroll
            for (int i = 0; i < 6; i++) {
                float s, c;
                __sincosf(0.5f * h[i], &s, &c);
                prod *= bitv[i] ? s : c;
            }
            re = prod;
        }

        // ---- QSVT block: per degree a diagonal phase + fixed CNOT permutation ----
#pragma unroll
        for (int d = 0; d < 4; d++) {
            float phi = 0.f;
#pragma unroll
            for (int i = 0; i < 6; i++) phi += (u[d][i] * dtv[i]) * sgn[i];
            float sphi, cphi;
            __sincosf(phi, &sphi, &cphi);
            float nr = re * cphi - im * sphi;
            float ni = re * sphi + im * cphi;
            re = __shfl(nr, src, 64);
            im = __shfl(ni, src, 64);
        }

        // ---- ansatz: 2 layers of (fused 1q gates + 2 CRX rings) ----
#pragma unroll
        for (int l = 0; l < 2; l++) {
#pragma unroll
            for (int i = 0; i < 6; i++) {
                int m = 32 >> i;
                float pre = shx(re, m), pim = shx(im, m);
                int bt = bitv[i];
                float arr = bt ? G11r[l][i] : G00r[l][i];
                float ari = bt ? G11i[l][i] : G00i[l][i];
                float brr = bt ? G10r[l][i] : G01r[l][i];
                float bri = bt ? G10i[l][i] : G01i[l][i];
                float nr = arr * re - ari * im + brr * pre - bri * pim;
                float ni = arr * im + ari * re + brr * pim + bri * pre;
                re = nr; im = ni;
            }
#pragma unroll
            for (int i = 0; i < 6; i++) {          // CRX(ctrl=i, tgt=(i+1)%6)
                int m = 32 >> ((i + 1) % 6);
                float pre = shx(re, m), pim = shx(im, m);
                int cb = bitv[i];
                float ce = cb ? CR1c[l][i] : 1.f;
                float se = cb ? CR1s[l][i] : 0.f;
                float nr = ce * re + se * pim;
                float ni = ce * im - se * pre;
                re = nr; im = ni;
            }
#pragma unroll
            for (int i = 5; i >= 0; i--) {         // CRX(ctrl=i, tgt=(i-1)%6), i descending
                int m = 32 >> ((i + 5) % 6);
                float pre = shx(re, m), pim = shx(im, m);
                int cb = bitv[i];
                float ce = cb ? CR2c[l][i] : 1.f;
                float se = cb ? CR2s[l][i] : 0.f;
                float nr = ce * re + se * pim;
                float ni = ce * im - se * pre;
                re = nr; im = ni;
            }
        }

        // ---- final RY(x_i*dt_i) layer (half-angle sincos precomputed) ----
#pragma unroll
        for (int i = 0; i < 6; i++) {
            int m = 32 >> i;
            float pre = shx(re, m), pim = shx(im, m);
            float e = bitv[i] ? shh[i] : -shh[i];
            float nr = chh[i] * re + e * pre;
            float ni = chh[i] * im + e * pim;
            re = nr; im = ni;
        }

        // ---- measurements ----
        float p = re * re + im * im;
        // all <Z_i> via one distributed Walsh-Hadamard transform
        float w = p;
#pragma unroll
        for (int k = 1; k < 64; k <<= 1) {
            float tw = shx(w, k);
            w = (lane & k) ? (tw - w) : (w + tw);
        }
        float X[6], Y[6], Z[6];
#pragma unroll
        for (int i = 0; i < 6; i++) {
            int m = 32 >> i;
            float pre = shx(re, m), pim = shx(im, m);
            float ur = re * pre + im * pim;   // Re(conj(own)*partner)
            float ui = re * pim - im * pre;   // Im(conj(own)*partner)
            float yc = bitv[i] ? -ui : ui;
#pragma unroll
            for (int k = 1; k < 64; k <<= 1) { ur += shx(ur, k); yc += shx(yc, k); }
            X[i] = ur;                         // 2*Re(z)
            Y[i] = yc;                         // 2*Im(z)
            Z[i] = __shfl(w, m, 64);           // Walsh coeff at lane 2^(5-i)
        }
#pragma unroll
        for (int i = 0; i < 6; i++) h[i] = Z[i];  // feedback

        if (lane == 0) {
            float* o = outb + t * 18;
#pragma unroll
            for (int i = 0; i < 6; i++) {
                o[i]      = r[18 + i] * X[i] + r[36 + i];
                o[6 + i]  = r[24 + i] * Y[i] + r[42 + i];
                o[12 + i] = r[30 + i] * Z[i] + r[48 + i];
            }
        }
    }
}

// ---------------------------------------------------------------------------
extern "C" void kernel_launch(void* const* d_in, const int* in_sizes, int n_in,
                              void* d_out, int out_size, void* d_ws, size_t ws_size,
                              hipStream_t stream) {
    const float* angles = (const float*)d_in[0];
    const float* Wx     = (const float*)d_in[1];
    const float* Wdt    = (const float*)d_in[2];
    const float* bdt    = (const float*)d_in[3];
    const float* pc     = (const float*)d_in[4];  // poly_coeffs
    const float* qp     = (const float*)d_in[5];  // qsvt_params
    const float* cp     = (const float*)d_in[6];  // circuit_params
    const float* D      = (const float*)d_in[7];
    const float* Wc     = (const float*)d_in[8];
    float* sd  = (float*)d_ws;   // 256*512*56 floats = ~28 MB
    float* out = (float*)d_out;

    prep_kernel<<<(BATCH * SEQ) / 256, 256, 0, stream>>>(angles, Wx, Wdt, bdt, D, Wc, sd);
    step_kernel<<<BATCH, 64, 0, stream>>>(sd, pc, qp, cp, out);
}

// Round 2
// 1070.113 us; speedup vs baseline: 1.6103x; 1.6103x over previous
//
#include <hip/hip_runtime.h>
#include <math.h>

#define BATCH 256
#define SEQ 512
#define SD_STRIDE 56   // dt[6] cos[6] sin[6] Cc[18] term[18] pad[2]
#define PI_F 3.14159265358979323846f

// ---- cross-lane helpers -----------------------------------------------------
template<int CTRL>
__device__ __forceinline__ float fdpp(float v) {
    return __int_as_float(__builtin_amdgcn_mov_dpp(__float_as_int(v), CTRL, 0xF, 0xF, true));
}
// xor-shuffle; masks 1,2,3 -> quad_perm DPP, 8 -> row_ror:8 DPP, else ds_bpermute
template<int M>
__device__ __forceinline__ float shxm(float v) {
    if constexpr (M == 1)      return fdpp<0xB1>(v);   // quad_perm [1,0,3,2]
    else if constexpr (M == 2) return fdpp<0x4E>(v);   // quad_perm [2,3,0,1]
    else if constexpr (M == 3) return fdpp<0x1B>(v);   // quad_perm [3,2,1,0]
    else if constexpr (M == 8) return fdpp<0x128>(v);  // row_ror:8 (xor8 within 16)
    else return __shfl_xor(v, M, 64);
}
template<int L>
__device__ __forceinline__ float rdl(float v) {
    return __int_as_float(__builtin_amdgcn_readlane(__float_as_int(v), L));
}
// fused radix-4 Hadamard/Walsh butterfly stage over qubit masks MI,MJ
// si/sj = (+1,-1) sign of this lane's MI/MJ qubit bit
template<int MI, int MJ>
__device__ __forceinline__ float bfly4(float v, float si, float sj, float sij) {
    float a = shxm<MI>(v), b = shxm<MJ>(v), c = shxm<MI|MJ>(v);
    return fmaf(sij, v, fmaf(sj, a, fmaf(si, b, c)));
}
// fused pair of 1q gates (complex 4-term gather); c[8] = {c00,c10,c01,c11} interleaved r,i
template<int MI, int MJ>
__device__ __forceinline__ void pair1q(float& re, float& im, const float* c) {
    float ar = shxm<MI>(re), ai = shxm<MI>(im);
    float br = shxm<MJ>(re), bi = shxm<MJ>(im);
    float cr = shxm<MI|MJ>(re), ci = shxm<MI|MJ>(im);
    float nr = c[0]*re - c[1]*im + c[2]*ar - c[3]*ai + c[4]*br - c[5]*bi + c[6]*cr - c[7]*ci;
    float ni = c[0]*im + c[1]*re + c[2]*ai + c[3]*ar + c[4]*bi + c[5]*br + c[6]*ci + c[7]*cr;
    re = nr; im = ni;
}
// fused chained CRX pair (a->b)(b->c): coefs R0 (own), i*i10 (flip b), i*i01 (flip c), R3 (both)
template<int MB, int MC>
__device__ __forceinline__ void ringop(float& re, float& im, float R0, float i10, float i01, float R3) {
    float br = shxm<MB>(re), bi = shxm<MB>(im);
    float cr = shxm<MC>(re), ci = shxm<MC>(im);
    float dr = shxm<MB|MC>(re), di = shxm<MB|MC>(im);
    float nr = R0*re - i10*bi - i01*ci + R3*dr;
    float ni = R0*im + i10*br + i01*cr + R3*di;
    re = nr; im = ni;
}
// the per-degree QSVT CNOT-block permutation (src map)
__device__ __forceinline__ int permf(int x) {
    const int cs[11] = {0,1,2,3,4,5,5,4,3,2,1};
    const int ts[11] = {1,2,3,4,5,0,4,3,2,1,0};
#pragma unroll
    for (int k = 10; k >= 0; k--) {
        int cb = (x >> (5 - cs[k])) & 1;
        x ^= cb << (5 - ts[k]);
    }
    return x;
}

// ---------------------------------------------------------------------------
__global__ __launch_bounds__(256) void prep_kernel(
    const float* __restrict__ angles, const float* __restrict__ Wx,
    const float* __restrict__ Wdt, const float* __restrict__ bdt,
    const float* __restrict__ D, const float* __restrict__ Wc,
    float* __restrict__ sd)
{
    int gid = blockIdx.x * blockDim.x + threadIdx.x;
    if (gid >= BATCH * SEQ) return;
    const float* a = angles + (size_t)gid * 6;
    float ang[6];
#pragma unroll
    for (int i = 0; i < 6; i++) ang[i] = a[i];
    float dtr[3];
#pragma unroll
    for (int r = 0; r < 3; r++) {
        float s = 0.f;
#pragma unroll
        for (int k = 0; k < 6; k++) s += ang[k] * Wx[r * 6 + k];
        dtr[r] = s;
    }
    float* rec = sd + (size_t)gid * SD_STRIDE;
    float dtv[6];
#pragma unroll
    for (int i = 0; i < 6; i++) {
        float x = bdt[i];
#pragma unroll
        for (int r = 0; r < 3; r++) x += dtr[r] * Wdt[i * 3 + r];
        float sp = (x > 15.f) ? x : log1pf(expf(x));
        dtv[i] = tanhf(sp) * PI_F;
        rec[i] = dtv[i];
        float th = ang[i] * dtv[i];        // FULL angle (RY folded into measurement rotation)
        rec[6 + i]  = cosf(th);
        rec[12 + i] = sinf(th);
    }
    float C[6];
#pragma unroll
    for (int i = 0; i < 6; i++) {
        float s = 0.f;
#pragma unroll
        for (int k = 0; k < 6; k++) s += ang[k] * Wx[(9 + i) * 6 + k];
        C[i] = s;
    }
#pragma unroll
    for (int j = 0; j < 18; j++) {
        float s = 0.f;
#pragma unroll
        for (int i = 0; i < 6; i++) s += C[i] * Wc[j * 6 + i];
        rec[18 + j] = s;
        rec[36 + j] = D[j] * ang[j % 6];
    }
}

// ---------------------------------------------------------------------------
__global__ __launch_bounds__(64, 1) void step_kernel(
    const float* __restrict__ sd, const float* __restrict__ pc,
    const float* __restrict__ qp, const float* __restrict__ cp,
    float* __restrict__ out, float* __restrict__ ws_dummy)
{
    const int lane = threadIdx.x;
    const int b = blockIdx.x;

    int bitv[6];
#pragma unroll
    for (int i = 0; i < 6; i++) bitv[i] = (lane >> (5 - i)) & 1;
    // Hadamard/Walsh signs
    float s0_ = bitv[0] ? -1.f : 1.f, s1_ = bitv[1] ? -1.f : 1.f;
    float s2_ = bitv[2] ? -1.f : 1.f, s3_ = bitv[3] ? -1.f : 1.f;
    float s4_ = bitv[4] ? -1.f : 1.f, s5_ = bitv[5] ? -1.f : 1.f;
    float s01 = s0_ * s1_, s23 = s2_ * s3_, s45 = s4_ * s5_;

    // writer lanes: popcount==1; lane 32>>i holds qubit i's Walsh coefficient
    bool isw = (__popc(lane) == 1);
    int qi = isw ? (5 - (31 - __clz(lane))) : 0;

    // S-dagger per-lane factor (-i)^popcount
    int kk = __popc(lane) & 3;
    float fr = (kk == 0) ? 1.f : ((kk == 2) ? -1.f : 0.f);
    float fi = (kk == 1) ? -1.f : ((kk == 3) ? 1.f : 0.f);

    // QSVT collapsed: phase coefs A[i] and final permutation sigma^4
    float A[6];
    int src4;
    {
        int x1 = permf(lane), x2 = permf(x1), x3 = permf(x2), x4 = permf(x3);
        src4 = x4;
#pragma unroll
        for (int i = 0; i < 6; i++) {
            float u0 = pc[0] * PI_F * qp[0 * 6 + i];
            float u1 = pc[1] * PI_F * qp[1 * 6 + i];
            float u2 = pc[2] * PI_F * qp[2 * 6 + i];
            float u3 = pc[3] * PI_F;
            float g1 = ((x1 >> (5 - i)) & 1) ? 0.5f : -0.5f;
            float g2 = ((x2 >> (5 - i)) & 1) ? 0.5f : -0.5f;
            float g3 = ((x3 >> (5 - i)) & 1) ? 0.5f : -0.5f;
            float g4 = ((x4 >> (5 - i)) & 1) ? 0.5f : -0.5f;
            A[i] = u3 * g1 + u2 * g2 + u1 * g3 + u0 * g4;
        }
    }

    // fused ansatz coefficients (per-lane, t-independent)
    float qc[2][3][8];   // 1q pairs (q0,q1),(q2,q3),(q4,q5)
    float rc[2][6][4];   // ring ops F0..F2,G0..G2
#pragma unroll
    for (int l = 0; l < 2; l++) {
        float g00r[6], g00i[6], g01r[6], g01i[6], g10r[6], g10i[6], g11r[6], g11i[6];
#pragma unroll
        for (int i = 0; i < 6; i++) {
            float ax = cp[l * 30 + i * 3 + 0];
            float ay = cp[l * 30 + i * 3 + 1];
            float az = cp[l * 30 + i * 3 + 2];
            float ca = cosf(0.5f * ax), sa = sinf(0.5f * ax);
            float cb = cosf(0.5f * ay), sb = sinf(0.5f * ay);
            float cg = cosf(0.5f * az), sg = sinf(0.5f * az);
            float m00r = cb * ca, m00i =  sb * sa;
            float m01r = -sb * ca, m01i = -cb * sa;
            float m10r =  sb * ca, m10i = -cb * sa;
            float m11r =  cb * ca, m11i = -sb * sa;
            g00r[i] = cg * m00r + sg * m00i; g00i[i] = cg * m00i - sg * m00r;
            g01r[i] = cg * m01r + sg * m01i; g01i[i] = cg * m01i - sg * m01r;
            g10r[i] = cg * m10r - sg * m10i; g10i[i] = cg * m10i + sg * m10r;
            g11r[i] = cg * m11r - sg * m11i; g11i[i] = cg * m11i + sg * m11r;
        }
#pragma unroll
        for (int pp = 0; pp < 3; pp++) {
            int aq = 2 * pp, bq = 2 * pp + 1;
            float dar = bitv[aq] ? g11r[aq] : g00r[aq], dai = bitv[aq] ? g11i[aq] : g00i[aq];
            float oar = bitv[aq] ? g10r[aq] : g01r[aq], oai = bitv[aq] ? g10i[aq] : g01i[aq];
            float dbr = bitv[bq] ? g11r[bq] : g00r[bq], dbi = bitv[bq] ? g11i[bq] : g00i[bq];
            float obr = bitv[bq] ? g10r[bq] : g01r[bq], obi = bitv[bq] ? g10i[bq] : g01i[bq];
            qc[l][pp][0] = dar * dbr - dai * dbi;  qc[l][pp][1] = dar * dbi + dai * dbr;
            qc[l][pp][2] = oar * dbr - oai * dbi;  qc[l][pp][3] = oar * dbi + oai * dbr;
            qc[l][pp][4] = dar * obr - dai * obi;  qc[l][pp][5] = dar * obi + dai * obr;
            qc[l][pp][6] = oar * obr - oai * obi;  qc[l][pp][7] = oar * obi + oai * obr;
        }
        // ring fused pairs: op -> (a=ctrl1, b=mid, angles)
        const int Aq[6] = {0, 2, 4, 5, 3, 1};
        const int Bq[6] = {1, 3, 5, 4, 2, 0};
#pragma unroll
        for (int o = 0; o < 6; o++) {
            float tha = (o < 3) ? cp[l * 30 + 18 + 2 * o]     : cp[l * 30 + 24 + 2 * (o - 3)];
            float thb = (o < 3) ? cp[l * 30 + 18 + 2 * o + 1] : cp[l * 30 + 24 + 2 * (o - 3) + 1];
            float ca = cosf(0.5f * tha), sa = sinf(0.5f * tha);
            float cb = cosf(0.5f * thb), sb = sinf(0.5f * thb);
            int ba = bitv[Aq[o]], bb = bitv[Bq[o]];
            float mx0 = ba ? ca : 1.f, sae = ba ? sa : 0.f;
            float ny0 = bb ? cb : 1.f, sbe = bb ? sb : 0.f;
            rc[l][o][0] = ny0 * mx0;
            rc[l][o][1] = -ny0 * sae;
            rc[l][o][2] = -mx0 * sbe;
            rc[l][o][3] = -sae * sbe;
        }
    }

    const float* sdb = sd + (size_t)b * SEQ * SD_STRIDE;
    float* outb = out + (size_t)b * SEQ * 18;

    float h0 = 0.f, h1 = 0.f, h2 = 0.f, h3 = 0.f, h4 = 0.f, h5 = 0.f;
    float pyr = 0.f, pyi = 0.f, pxm = 0.f, pzm = 0.f;
    float pcx = 0.f, pcy = 0.f, pcz = 0.f, ptx = 0.f, pty = 0.f, ptz = 0.f;

    // Y measurement of a saved state (basis change (H S^dag)^x6 then Walsh)
    auto ymeas = [&](float ar, float ai) -> float {
        float cr = fr * ar - fi * ai;
        float ci = fr * ai + fi * ar;
        float t0 = bfly4<2, 1>(cr, s4_, s5_, s45);
        float t1 = bfly4<2, 1>(ci, s4_, s5_, s45);
        cr = bfly4<8, 4>(t0, s2_, s3_, s23);
        ci = bfly4<8, 4>(t1, s2_, s3_, s23);
        t0 = bfly4<32, 16>(cr, s0_, s1_, s01);
        t1 = bfly4<32, 16>(ci, s0_, s1_, s01);
        float p2 = t0 * t0 + t1 * t1;
        float w2 = bfly4<2, 1>(p2, s4_, s5_, s45);
        w2 = bfly4<8, 4>(w2, s2_, s3_, s23);
        w2 = bfly4<32, 16>(w2, s0_, s1_, s01);
        return w2 * 0.015625f;
    };

    for (int t = 0; t < SEQ; t++) {
        const float* r = sdb + t * SD_STRIDE;
        float d0 = r[0], d1 = r[1], d2 = r[2], d3 = r[3], d4 = r[4], d5 = r[5];
        float ct = r[6 + qi], st2 = r[12 + qi];
        float cx = r[18 + qi], cy = r[24 + qi], cz = r[30 + qi];
        float tx = r[36 + qi], ty = r[42 + qi], tz = r[48 + qi];

        // deferred Y of step t-1 (independent of h-chain; scheduler interleaves)
        float ym = ymeas(pyr, pyi);

        // ---- product state RY(h)|0..0> ----
        float prod;
        {
            float s, c;
            __sincosf(0.5f * h0, &s, &c); prod  = bitv[0] ? s : c;
            __sincosf(0.5f * h1, &s, &c); prod *= bitv[1] ? s : c;
            __sincosf(0.5f * h2, &s, &c); prod *= bitv[2] ? s : c;
            __sincosf(0.5f * h3, &s, &c); prod *= bitv[3] ? s : c;
            __sincosf(0.5f * h4, &s, &c); prod *= bitv[4] ? s : c;
            __sincosf(0.5f * h5, &s, &c); prod *= bitv[5] ? s : c;
        }

        // ---- QSVT collapsed: permutation sigma^4 then single diagonal phase ----
        float phi = A[0] * d0 + A[1] * d1 + A[2] * d2 + A[3] * d3 + A[4] * d4 + A[5] * d5;
        float sph, cph;
        __sincosf(phi, &sph, &cph);
        float pr = __shfl(prod, src4, 64);     // state real here -> one shuffle
        float re = pr * cph;
        float im = pr * sph;

        // ---- ansatz: 2 layers x (3 fused 1q pairs + 6 fused CRX pairs) ----
#pragma unroll
        for (int l = 0; l < 2; l++) {
            pair1q<32, 16>(re, im, qc[l][0]);
            pair1q<8, 4>(re, im, qc[l][1]);
            pair1q<2, 1>(re, im, qc[l][2]);
            ringop<16, 8>(re, im, rc[l][0][0], rc[l][0][1], rc[l][0][2], rc[l][0][3]);  // (0->1)(1->2)
            ringop<4, 2>(re, im, rc[l][1][0], rc[l][1][1], rc[l][1][2], rc[l][1][3]);   // (2->3)(3->4)
            ringop<1, 32>(re, im, rc[l][2][0], rc[l][2][1], rc[l][2][2], rc[l][2][3]);  // (4->5)(5->0)
            ringop<2, 4>(re, im, rc[l][3][0], rc[l][3][1], rc[l][3][2], rc[l][3][3]);   // (5->4)(4->3)
            ringop<8, 16>(re, im, rc[l][4][0], rc[l][4][1], rc[l][4][2], rc[l][4][3]);  // (3->2)(2->1)
            ringop<32, 1>(re, im, rc[l][5][0], rc[l][5][1], rc[l][5][2], rc[l][5][3]);  // (1->0)(0->5)
        }

        // ---- measurements (final RY folded into expectation rotation) ----
        float p = re * re + im * im;
        float w = bfly4<2, 1>(p, s4_, s5_, s45);
        w = bfly4<8, 4>(w, s2_, s3_, s23);
        w = bfly4<32, 16>(w, s0_, s1_, s01);          // Z_i at lane 32>>i

        float xr = re, xi = im;
        {
            float t0 = bfly4<2, 1>(xr, s4_, s5_, s45);
            float t1 = bfly4<2, 1>(xi, s4_, s5_, s45);
            xr = bfly4<8, 4>(t0, s2_, s3_, s23);
            xi = bfly4<8, 4>(t1, s2_, s3_, s23);
            t0 = bfly4<32, 16>(xr, s0_, s1_, s01);
            t1 = bfly4<32, 16>(xi, s0_, s1_, s01);
            xr = t0; xi = t1;
        }
        float p1 = xr * xr + xi * xi;
        float w1 = bfly4<2, 1>(p1, s4_, s5_, s45);
        w1 = bfly4<8, 4>(w1, s2_, s3_, s23);
        w1 = bfly4<32, 16>(w1, s0_, s1_, s01);        // 64*X_i at lane 32>>i

        float Zl = w;
        float Xl = w1 * 0.015625f;
        float zm = ct * Zl - st2 * Xl;                 // Z after folded RY
        float xm = ct * Xl + st2 * Zl;                 // X after folded RY

        h0 = rdl<32>(zm); h1 = rdl<16>(zm); h2 = rdl<8>(zm);
        h3 = rdl<4>(zm);  h4 = rdl<2>(zm);  h5 = rdl<1>(zm);

        // ---- store step t-1 outputs (Y just computed) ----
        if (isw && t > 0) {
            float* o = outb + (size_t)(t - 1) * 18;
            o[qi]      = fmaf(pcx, pxm, ptx);
            o[6 + qi]  = fmaf(pcy, ym, pty);
            o[12 + qi] = fmaf(pcz, pzm, ptz);
        }
        pyr = re; pyi = im; pxm = xm; pzm = zm;
        pcx = cx; pcy = cy; pcz = cz; ptx = tx; pty = ty; ptz = tz;
    }
    // epilogue: last step's Y + store
    float ym = ymeas(pyr, pyi);
    if (isw) {
        float* o = outb + (size_t)(SEQ - 1) * 18;
        o[qi]      = fmaf(pcx, pxm, ptx);
        o[6 + qi]  = fmaf(pcy, ym, pty);
        o[12 + qi] = fmaf(pcz, pzm, ptz);
    }
    (void)ws_dummy;
}

// ---------------------------------------------------------------------------
extern "C" void kernel_launch(void* const* d_in, const int* in_sizes, int n_in,
                              void* d_out, int out_size, void* d_ws, size_t ws_size,
                              hipStream_t stream) {
    const float* angles = (const float*)d_in[0];
    const float* Wx     = (const float*)d_in[1];
    const float* Wdt    = (const float*)d_in[2];
    const float* bdt    = (const float*)d_in[3];
    const float* pc     = (const float*)d_in[4];
    const float* qp     = (const float*)d_in[5];
    const float* cp     = (const float*)d_in[6];
    const float* D      = (const float*)d_in[7];
    const float* Wc     = (const float*)d_in[8];
    float* sd  = (float*)d_ws;
    float* out = (float*)d_out;

    prep_kernel<<<(BATCH * SEQ) / 256, 256, 0, stream>>>(angles, Wx, Wdt, bdt, D, Wc, sd);
    step_kernel<<<BATCH, 64, 0, stream>>>(sd, pc, qp, cp, out, sd);
}